// Round 5
// baseline (298356.689 us; speedup 1.0000x reference)
//
#include <hip/hip_runtime.h>
#include <hip/hip_bf16.h>
#include <math.h>

#define T_STEPS 8192
#define NN      1024
#define KWG     32       // WGs per team (one team per XCD, 8 teams, redundant)
#define NTEAM   8
#define RT      512
#define NWG_LAUNCH 1024  // candidates; non-claimers exit immediately
#define FAST_SPIN 64     // sc0 poll iterations before agent-scope fallback

__device__ __forceinline__ float fast_sigmoid(float z) {
    z = fminf(fmaxf(z, -30.f), 30.f);
    return 1.f / (1.f + __expf(-z));
}
__device__ __forceinline__ float fast_tanh(float x) {
    x = fminf(fmaxf(x, -9.f), 9.f);
    const float e = __expf(2.f * x);
    return (e - 1.f) / (e + 1.f);
}

// Two-tier store: sc0 copy stays in this XCD's L2 (fast path for same-XCD
// readers); agent-scope mirror guarantees LLC visibility (fallback path).
__device__ __forceinline__ void st_u64_2way(unsigned long long* p, unsigned long long v) {
    asm volatile("global_store_dwordx2 %0, %1, off sc0" :: "v"(p), "v"(v) : "memory");
    __hip_atomic_store(p, v, __ATOMIC_RELAXED, __HIP_MEMORY_SCOPE_AGENT);
}

// Two-tier tagged poll of two u64 slots: bounded sc0 spin, then unbounded
// agent-scope spin (R1-R3-proven coherent). Hang-proof by construction.
__device__ __forceinline__ void poll2(const unsigned long long* pa,
                                      const unsigned long long* pb,
                                      unsigned tag,
                                      unsigned long long& va, unsigned long long& vb) {
    bool fa = false, fb = false;
    for (int it = 0; it < FAST_SPIN; ++it) {
        unsigned long long xa, xb;
        asm volatile("global_load_dwordx2 %0, %2, off sc0\n\t"
                     "global_load_dwordx2 %1, %3, off sc0\n\t"
                     "s_waitcnt vmcnt(0)"
                     : "=&v"(xa), "=&v"(xb) : "v"(pa), "v"(pb) : "memory");
        if (!fa && (unsigned)(xa >> 32) == tag) { va = xa; fa = true; }
        if (!fb && (unsigned)(xb >> 32) == tag) { vb = xb; fb = true; }
        if (fa && fb) return;
    }
    for (;;) {
        if (!fa) {
            const unsigned long long xa =
                __hip_atomic_load(pa, __ATOMIC_RELAXED, __HIP_MEMORY_SCOPE_AGENT);
            if ((unsigned)(xa >> 32) == tag) { va = xa; fa = true; }
        }
        if (!fb) {
            const unsigned long long xb =
                __hip_atomic_load(pb, __ATOMIC_RELAXED, __HIP_MEMORY_SCOPE_AGENT);
            if ((unsigned)(xb >> 32) == tag) { vb = xb; fb = true; }
        }
        if (fa && fb) return;
    }
}

// ---------------- GEMM: C[8192,1024] = A[8192,1024] @ W[1024,1024] + bias ----
__global__ __launch_bounds__(256) void gemm_bias(
    const float* __restrict__ A, const float* __restrict__ W,
    const float* __restrict__ bias, float* __restrict__ C)
{
    const int bn = blockIdx.x;
    const int bm = blockIdx.y;
    const int tid = threadIdx.x;

    __shared__ __align__(16) float As[16][68];
    __shared__ __align__(16) float Bs[16][68];

    const int row0 = bm * 64, col0 = bn * 64;
    const int tm = (tid >> 4) << 2;
    const int tn = (tid & 15) << 2;

    float acc[4][4] = {};

    for (int k0 = 0; k0 < 1024; k0 += 16) {
        {
            const int m = tid >> 2, kq = (tid & 3) << 2;
            const float4 v = *reinterpret_cast<const float4*>(&A[(size_t)(row0 + m) * 1024 + k0 + kq]);
            As[kq + 0][m] = v.x; As[kq + 1][m] = v.y; As[kq + 2][m] = v.z; As[kq + 3][m] = v.w;
            const int kk = tid >> 4, nq = (tid & 15) << 2;
            *reinterpret_cast<float4*>(&Bs[kk][nq]) =
                *reinterpret_cast<const float4*>(&W[(size_t)(k0 + kk) * 1024 + col0 + nq]);
        }
        __syncthreads();
#pragma unroll
        for (int k = 0; k < 16; ++k) {
            const float4 a4 = *reinterpret_cast<const float4*>(&As[k][tm]);
            const float4 b4 = *reinterpret_cast<const float4*>(&Bs[k][tn]);
            const float a[4] = {a4.x, a4.y, a4.z, a4.w};
            const float b[4] = {b4.x, b4.y, b4.z, b4.w};
#pragma unroll
            for (int i = 0; i < 4; ++i)
#pragma unroll
                for (int j = 0; j < 4; ++j) acc[i][j] += a[i] * b[j];
        }
        __syncthreads();
    }
#pragma unroll
    for (int i = 0; i < 4; ++i)
#pragma unroll
        for (int j = 0; j < 4; ++j)
            C[(size_t)(row0 + tm + i) * 1024 + col0 + tn + j] = acc[i][j] + bias[col0 + tn + j];
}

// ---------------- Recurrent scan: 8 redundant XCD-local teams ---------------
// Team = first 32 WGs arriving on an XCD (per-XCD arrival counter). Each team
// runs the full recurrence in its own P/h buffers; outputs are bitwise
// identical, duplicate out-stores benign. Exchange per step (owner-reduce):
//   p1: r_j local | B1 | p2: rank-32 partials -> 2-way tagged stores
//   RT1: owner polls 32 partials (1 poller/slot), reduce, tanh, out, h-cast
//   RT2: all poll tagged h, refill LDS | B2
__global__ __launch_bounds__(RT, 1) void gru_rec(
    const float* __restrict__ xT, const float* __restrict__ xR,
    const float* __restrict__ hRW, const float* __restrict__ hW,
    const float* __restrict__ hRB, const float* __restrict__ hB,
    const float* __restrict__ h0, float* __restrict__ out,
    unsigned long long* __restrict__ P,     // [NTEAM][2][KWG][NN]
    unsigned long long* __restrict__ hbc,   // [NTEAM][2][NN]
    unsigned int* __restrict__ cnt)         // [NTEAM] arrival counters
{
    const int tid = threadIdx.x;

    __shared__ int s_team, s_g;
    if (tid == 0) {
        unsigned xcc;
        asm volatile("s_getreg_b32 %0, hwreg(HW_REG_XCC_ID)" : "=s"(xcc));
        xcc &= (NTEAM - 1);
        const unsigned s = atomicAdd(&cnt[xcc], 1u);
        s_team = (int)xcc;
        s_g = (s < KWG) ? (int)s : -1;
    }
    __syncthreads();
    const int g = s_g;
    if (g < 0) return;   // uniform across WG
    const int team = s_team;

    unsigned long long* __restrict__ Pt  = P   + (size_t)team * 2 * KWG * NN;
    unsigned long long* __restrict__ Hbt = hbc + (size_t)team * 2 * NN;

    const int lane = tid & 63;
    const int wave = tid >> 6;

    __shared__ __align__(16) float hsh[1088];  // 64-chunk c at c*68
    __shared__ __align__(16) float rh[32];

    // phase 1: own column j (0..31), 16 lanes (c) split i into 64-chunks
    const int j = (wave << 2) | (lane >> 4);
    const int c = lane & 15;
    const bool leader1 = (c == 0);
    float w1[64];
#pragma unroll
    for (int k = 0; k < 64; ++k)
        w1[k] = hRW[(size_t)(c * 64 + k) * NN + g * 32 + j];

    // phase 2: thread owns outputs n0, n1
    const int n0 = tid, n1 = tid + RT;
    const int pi0 = n0 + (n0 >> 6) * 4, pi1 = n1 + (n1 >> 6) * 4;
    float w2a[32], w2b[32];
#pragma unroll
    for (int k = 0; k < 32; ++k) {
        w2a[k] = hW[(size_t)(g * 32 + k) * NN + n0];
        w2b[k] = hW[(size_t)(g * 32 + k) * NN + n1];
    }
    // Pin weights in VGPRs: opaque asm "write" prevents the compiler from
    // rematerializing these loads inside the step loop (R1-R3 hidden cost:
    // VGPR_Count 92 proved the 128 floats were NOT register-resident).
#pragma unroll
    for (int k = 0; k < 64; ++k) asm volatile("" : "+v"(w1[k]));
#pragma unroll
    for (int k = 0; k < 32; ++k) asm volatile("" : "+v"(w2a[k]));
#pragma unroll
    for (int k = 0; k < 32; ++k) asm volatile("" : "+v"(w2b[k]));

    // owner-reduce mapping: column jj (0..31) x 16 reducer lanes (cc)
    const int jj = tid >> 4, cc = tid & 15;
    const bool eleader = (cc == 0);
    const int mjj = g * 32 + jj;
    const float hBo = hB[mjj];

    const int mj = g * 32 + j;
    const int pij = mj + (mj >> 6) * 4;
    const float hRBj = hRB[mj];

    hsh[pi0] = h0[n0];
    hsh[pi1] = h0[n1];
    __syncthreads();

    float xr_n  = leader1 ? xR[mj]  : 0.f;
    float xto_n = eleader ? xT[mjj] : 0.f;

    for (int t = 0; t < T_STEPS; ++t) {
        const unsigned tag = (unsigned)(t + 1);
        unsigned long long* __restrict__ Pb = Pt  + (size_t)(t & 1) * KWG * NN;
        unsigned long long* __restrict__ Hb = Hbt + (size_t)(t & 1) * NN;

        const float xr = xr_n, xto = xto_n;
        if (t + 1 < T_STEPS) {
            if (leader1) xr_n  = xR[(size_t)(t + 1) * NN + mj];
            if (eleader) xto_n = xT[(size_t)(t + 1) * NN + mjj];
        }

        // ---- phase 1: r-gemv partials over own 64-chunk
        float a0 = 0.f, a1 = 0.f, a2 = 0.f, a3 = 0.f;
#pragma unroll
        for (int k = 0; k < 64; k += 4) {
            const float4 hv = *reinterpret_cast<const float4*>(&hsh[c * 68 + k]);
            a0 += hv.x * w1[k + 0]; a1 += hv.y * w1[k + 1];
            a2 += hv.z * w1[k + 2]; a3 += hv.w * w1[k + 3];
        }
        float s = (a0 + a1) + (a2 + a3);
        s += __shfl_xor(s, 1); s += __shfl_xor(s, 2);
        s += __shfl_xor(s, 4); s += __shfl_xor(s, 8);
        if (leader1) rh[j] = fast_sigmoid(xr + hRBj + s) * hsh[pij];
        __syncthreads();

        // ---- phase 2: rank-32 partials for n0, n1; 2-way tagged stores
        float b0 = 0.f, b1 = 0.f, d0 = 0.f, d1 = 0.f;
#pragma unroll
        for (int k = 0; k < 32; k += 2) {
            const float2 rv = *reinterpret_cast<const float2*>(&rh[k]);
            b0 += rv.x * w2a[k]; b1 += rv.y * w2a[k + 1];
            d0 += rv.x * w2b[k]; d1 += rv.y * w2b[k + 1];
        }
        st_u64_2way(&Pb[(size_t)g * NN + n0],
                    ((unsigned long long)tag << 32) | (unsigned)__float_as_uint(b0 + b1));
        st_u64_2way(&Pb[(size_t)g * NN + n1],
                    ((unsigned long long)tag << 32) | (unsigned)__float_as_uint(d0 + d1));

        // ---- RT1: owner-reduce — poll partials from regions cc and cc+16
        {
            unsigned long long va, vb;
            poll2(&Pb[(size_t)cc * NN + mjj], &Pb[(size_t)(cc + 16) * NN + mjj],
                  tag, va, vb);
            float s2 = __uint_as_float((unsigned)va) + __uint_as_float((unsigned)vb);
            s2 += __shfl_xor(s2, 1); s2 += __shfl_xor(s2, 2);
            s2 += __shfl_xor(s2, 4); s2 += __shfl_xor(s2, 8);
            if (eleader) {
                const float hn = fast_tanh(xto + s2 + hBo);
                out[(size_t)t * NN + mjj] = hn;
                st_u64_2way(&Hb[mjj],
                            ((unsigned long long)tag << 32) | (unsigned)__float_as_uint(hn));
            }
        }

        // ---- RT2: poll h broadcast, refill LDS h
        {
            unsigned long long ua, ub;
            poll2(&Hb[n0], &Hb[n1], tag, ua, ub);
            hsh[pi0] = __uint_as_float((unsigned)ua);
            hsh[pi1] = __uint_as_float((unsigned)ub);
        }
        __syncthreads();
    }
}

extern "C" void kernel_launch(void* const* d_in, const int* in_sizes, int n_in,
                              void* d_out, int out_size, void* d_ws, size_t ws_size,
                              hipStream_t stream) {
    const float* x   = (const float*)d_in[0];
    const float* Wx  = (const float*)d_in[1];
    const float* bx  = (const float*)d_in[2];
    // d_in[3]=Wu, d_in[4]=bu unused: update gate cancels in the reference
    const float* Wr  = (const float*)d_in[5];
    const float* br  = (const float*)d_in[6];
    const float* hW  = (const float*)d_in[7];
    // d_in[8]=hUW unused
    const float* hRW = (const float*)d_in[9];
    const float* hB  = (const float*)d_in[10];
    // d_in[11]=hUB unused
    const float* hRB = (const float*)d_in[12];
    const float* h0  = (const float*)d_in[13];
    float* out = (float*)d_out;

    char* ws = (char*)d_ws;
    float* xT = (float*)(ws);                    // 32 MB
    float* xR = (float*)(ws + 33554432);         // 32 MB
    unsigned int* cnt = (unsigned int*)(ws + 67108864);                    // 4 KB pad
    unsigned long long* P   = (unsigned long long*)(ws + 67108864 + 4096); // 4 MB
    unsigned long long* hbc = (unsigned long long*)(ws + 67108864 + 4096
                                + (size_t)NTEAM * 2 * KWG * NN * 8);       // 128 KB

    // zero counters + tags each launch (graph-replayed; also covers first-run
    // garbage and the harness's 0xAA poison)
    hipMemsetAsync(ws + 67108864, 0,
                   4096 + (size_t)NTEAM * 2 * KWG * NN * 8
                        + (size_t)NTEAM * 2 * NN * 8, stream);

    gemm_bias<<<dim3(16, 128), 256, 0, stream>>>(x, Wx, bx, xT);
    gemm_bias<<<dim3(16, 128), 256, 0, stream>>>(x, Wr, br, xR);

    gru_rec<<<dim3(NWG_LAUNCH), RT, 0, stream>>>(xT, xR, hRW, hW, hRB, hB, h0,
                                                 out, P, hbc, cnt);
}

// Round 6
// 31279.050 us; speedup vs baseline: 9.5385x; 9.5385x over previous
//
#include <hip/hip_runtime.h>
#include <hip/hip_bf16.h>
#include <math.h>

#define T_STEPS 8192
#define NN      1024
#define KWG     32
#define RT      512

typedef float f32x4 __attribute__((ext_vector_type(4)));

#define REP16(X) X(0) X(1) X(2) X(3) X(4) X(5) X(6) X(7) \
                 X(8) X(9) X(10) X(11) X(12) X(13) X(14) X(15)
#define REP8(X)  X(0) X(1) X(2) X(3) X(4) X(5) X(6) X(7)

__device__ __forceinline__ float fast_sigmoid(float z) {
    z = fminf(fmaxf(z, -30.f), 30.f);
    return 1.f / (1.f + __expf(-z));
}
__device__ __forceinline__ float fast_tanh(float x) {
    x = fminf(fmaxf(x, -9.f), 9.f);
    const float e = __expf(2.f * x);
    return (e - 1.f) / (e + 1.f);
}

// ---------------- GEMM: C[8192,1024] = A[8192,1024] @ W[1024,1024] + bias ----
__global__ __launch_bounds__(256) void gemm_bias(
    const float* __restrict__ A, const float* __restrict__ W,
    const float* __restrict__ bias, float* __restrict__ C)
{
    const int bn = blockIdx.x;
    const int bm = blockIdx.y;
    const int tid = threadIdx.x;

    __shared__ __align__(16) float As[16][68];
    __shared__ __align__(16) float Bs[16][68];

    const int row0 = bm * 64, col0 = bn * 64;
    const int tm = (tid >> 4) << 2;
    const int tn = (tid & 15) << 2;

    float acc[4][4] = {};

    for (int k0 = 0; k0 < 1024; k0 += 16) {
        {
            const int m = tid >> 2, kq = (tid & 3) << 2;
            const float4 v = *reinterpret_cast<const float4*>(&A[(size_t)(row0 + m) * 1024 + k0 + kq]);
            As[kq + 0][m] = v.x; As[kq + 1][m] = v.y; As[kq + 2][m] = v.z; As[kq + 3][m] = v.w;
            const int kk = tid >> 4, nq = (tid & 15) << 2;
            *reinterpret_cast<float4*>(&Bs[kk][nq]) =
                *reinterpret_cast<const float4*>(&W[(size_t)(k0 + kk) * 1024 + col0 + nq]);
        }
        __syncthreads();
#pragma unroll
        for (int k = 0; k < 16; ++k) {
            const float4 a4 = *reinterpret_cast<const float4*>(&As[k][tm]);
            const float4 b4 = *reinterpret_cast<const float4*>(&Bs[k][tn]);
            const float a[4] = {a4.x, a4.y, a4.z, a4.w};
            const float b[4] = {b4.x, b4.y, b4.z, b4.w};
#pragma unroll
            for (int i = 0; i < 4; ++i)
#pragma unroll
                for (int j = 0; j < 4; ++j) acc[i][j] += a[i] * b[j];
        }
        __syncthreads();
    }
#pragma unroll
    for (int i = 0; i < 4; ++i)
#pragma unroll
        for (int j = 0; j < 4; ++j)
            C[(size_t)(row0 + tm + i) * 1024 + col0 + tn + j] = acc[i][j] + bias[col0 + tn + j];
}

// ---------------- Recurrent scan (R3 structure + register-resident weights) --
// 32 persistent WGs. Per step:
//   p1: r_j partial dots (weights w1_* in VGPRs) | B1
//   p2: rank-32 partials (w2a_*/w2b_* in VGPRs) -> tagged agent stores
//   RT1: owner polls 32 partials (1 poller/slot), butterfly-reduce, tanh
//        -> tagged h broadcast (lane0) + out store (lane1)
//   RT2: all poll tagged h, refill LDS | B2
// Weights are NAMED f32x4 values laundered through asm ("+v"): not memory-
// derived, cannot be rematerialized or scratch-demoted (R1-R5: VGPR_Count
// ~96 proved they reloaded from L1/L2 every step = the 1.7us/step invariant).
__global__ __launch_bounds__(RT, 1) void gru_rec(
    const float* __restrict__ xT, const float* __restrict__ xR,
    const float* __restrict__ hRW, const float* __restrict__ hW,
    const float* __restrict__ hRB, const float* __restrict__ hB,
    const float* __restrict__ h0, float* __restrict__ out,
    unsigned long long* __restrict__ P,     // [2][KWG][NN]
    unsigned long long* __restrict__ hbc)   // [2][NN]
{
    const int g = blockIdx.x;
    const int tid = threadIdx.x;
    const int lane = tid & 63;
    const int wave = tid >> 6;

    __shared__ __align__(16) float hsh[1088];  // chunk c at c*68 (2-way max)
    __shared__ __align__(16) float rh[32];

    // phase 1 mapping: column j (0..31), 16 lanes (c) split i into 64-chunks
    const int j = (wave << 2) | (lane >> 4);
    const int c = lane & 15;
    const bool leader1 = (c == 0);
    const int colj = g * 32 + j;

    // ---- weights: named vectors, register-pinned ----
#define LD_W1(q) f32x4 w1_##q = { \
        hRW[(size_t)(c * 64 + 4 * q + 0) * NN + colj], \
        hRW[(size_t)(c * 64 + 4 * q + 1) * NN + colj], \
        hRW[(size_t)(c * 64 + 4 * q + 2) * NN + colj], \
        hRW[(size_t)(c * 64 + 4 * q + 3) * NN + colj] };
    REP16(LD_W1)

    const int n0 = tid, n1 = tid + RT;
    const int pi0 = n0 + (n0 >> 6) * 4, pi1 = n1 + (n1 >> 6) * 4;
#define LD_W2A(q) f32x4 w2a_##q = { \
        hW[(size_t)(g * 32 + 4 * q + 0) * NN + n0], \
        hW[(size_t)(g * 32 + 4 * q + 1) * NN + n0], \
        hW[(size_t)(g * 32 + 4 * q + 2) * NN + n0], \
        hW[(size_t)(g * 32 + 4 * q + 3) * NN + n0] };
    REP8(LD_W2A)
#define LD_W2B(q) f32x4 w2b_##q = { \
        hW[(size_t)(g * 32 + 4 * q + 0) * NN + n1], \
        hW[(size_t)(g * 32 + 4 * q + 1) * NN + n1], \
        hW[(size_t)(g * 32 + 4 * q + 2) * NN + n1], \
        hW[(size_t)(g * 32 + 4 * q + 3) * NN + n1] };
    REP8(LD_W2B)

#define PIN_W1(q)  asm volatile("" : "+v"(w1_##q));
#define PIN_W2A(q) asm volatile("" : "+v"(w2a_##q));
#define PIN_W2B(q) asm volatile("" : "+v"(w2b_##q));
    REP16(PIN_W1)
    REP8(PIN_W2A)
    REP8(PIN_W2B)

    // owner-reduce mapping: column jj (0..31) x 16 reducer lanes (cc)
    const int jj = tid >> 4, cc = tid & 15;
    const int mjj = g * 32 + jj;
    const float hBo = hB[mjj];

    const int mj = colj;
    const int pij = mj + (mj >> 6) * 4;
    const float hRBj = hRB[mj];

    hsh[pi0] = h0[n0];
    hsh[pi1] = h0[n1];
    __syncthreads();

    // 1-step-ahead input prefetch (hides HBM latency of the xT/xR stream)
    float xr_n  = leader1   ? xR[mj]  : 0.f;
    float xto_n = (cc == 0) ? xT[mjj] : 0.f;

    for (int t = 0; t < T_STEPS; ++t) {
        const unsigned tag = (unsigned)(t + 1);
        unsigned long long* __restrict__ Pb = P   + (size_t)(t & 1) * KWG * NN;
        unsigned long long* __restrict__ Hb = hbc + (size_t)(t & 1) * NN;

        const float xr = xr_n, xto = xto_n;
        if (t + 1 < T_STEPS) {
            if (leader1) xr_n  = xR[(size_t)(t + 1) * NN + mj];
            if (cc == 0) xto_n = xT[(size_t)(t + 1) * NN + mjj];
        }

        // ---- phase 1: r-gemv partials over own 64-chunk (weights in VGPRs)
        f32x4 acc = {0.f, 0.f, 0.f, 0.f};
#define FMA_W1(q) { \
        const f32x4 hv = *reinterpret_cast<const f32x4*>(&hsh[c * 68 + 4 * q]); \
        acc += hv * w1_##q; }
        REP16(FMA_W1)
        float s = (acc.x + acc.y) + (acc.z + acc.w);
        s += __shfl_xor(s, 1); s += __shfl_xor(s, 2);
        s += __shfl_xor(s, 4); s += __shfl_xor(s, 8);
        if (leader1) rh[j] = fast_sigmoid(xr + hRBj + s) * hsh[pij];
        __syncthreads();

        // ---- phase 2: rank-32 partials for n0, n1 (weights in VGPRs)
        f32x4 aa = {0.f, 0.f, 0.f, 0.f}, bb = {0.f, 0.f, 0.f, 0.f};
#define FMA_W2(q) { \
        const f32x4 rv = *reinterpret_cast<const f32x4*>(&rh[4 * q]); \
        aa += rv * w2a_##q; bb += rv * w2b_##q; }
        REP8(FMA_W2)
        const float p0 = (aa.x + aa.y) + (aa.z + aa.w);
        const float p1 = (bb.x + bb.y) + (bb.z + bb.w);
        __hip_atomic_store(&Pb[(size_t)g * NN + n0],
            ((unsigned long long)tag << 32) | (unsigned)__float_as_uint(p0),
            __ATOMIC_RELAXED, __HIP_MEMORY_SCOPE_AGENT);
        __hip_atomic_store(&Pb[(size_t)g * NN + n1],
            ((unsigned long long)tag << 32) | (unsigned)__float_as_uint(p1),
            __ATOMIC_RELAXED, __HIP_MEMORY_SCOPE_AGENT);

        // ---- RT1: owner-reduce — poll partials from regions cc and cc+16
        float hn;
        {
            unsigned long long va = 0, vb = 0;
            bool fa = false, fb = false;
            do {
                if (!fa) { va = __hip_atomic_load(&Pb[(size_t)cc * NN + mjj],
                             __ATOMIC_RELAXED, __HIP_MEMORY_SCOPE_AGENT);
                           fa = ((unsigned)(va >> 32) == tag); }
                if (!fb) { vb = __hip_atomic_load(&Pb[(size_t)(cc + 16) * NN + mjj],
                             __ATOMIC_RELAXED, __HIP_MEMORY_SCOPE_AGENT);
                           fb = ((unsigned)(vb >> 32) == tag); }
            } while (!(fa && fb));
            float s2 = __uint_as_float((unsigned)va) + __uint_as_float((unsigned)vb);
            s2 += __shfl_xor(s2, 1); s2 += __shfl_xor(s2, 2);
            s2 += __shfl_xor(s2, 4); s2 += __shfl_xor(s2, 8);
            hn = fast_tanh(xto ? xto + s2 + hBo : s2 + hBo);
            // all 16 lanes hold s2; recompute hn uniformly to split stores
            hn = fast_tanh(__shfl(xto, (tid & ~15) & 63, 64) + s2 + hBo);
            if (cc == 0) {
                __hip_atomic_store(&Hb[mjj],
                    ((unsigned long long)tag << 32) | (unsigned)__float_as_uint(hn),
                    __ATOMIC_RELAXED, __HIP_MEMORY_SCOPE_AGENT);
            }
            if (cc == 1) out[(size_t)t * NN + mjj] = hn;
        }

        // ---- RT2: poll h broadcast, refill LDS h
        {
            unsigned long long ua = 0, ub = 0;
            bool fa = false, fb = false;
            do {
                if (!fa) { ua = __hip_atomic_load(&Hb[n0], __ATOMIC_RELAXED,
                             __HIP_MEMORY_SCOPE_AGENT);
                           fa = ((unsigned)(ua >> 32) == tag); }
                if (!fb) { ub = __hip_atomic_load(&Hb[n1], __ATOMIC_RELAXED,
                             __HIP_MEMORY_SCOPE_AGENT);
                           fb = ((unsigned)(ub >> 32) == tag); }
            } while (!(fa && fb));
            hsh[pi0] = __uint_as_float((unsigned)ua);
            hsh[pi1] = __uint_as_float((unsigned)ub);
        }
        __syncthreads();
    }
}

extern "C" void kernel_launch(void* const* d_in, const int* in_sizes, int n_in,
                              void* d_out, int out_size, void* d_ws, size_t ws_size,
                              hipStream_t stream) {
    const float* x   = (const float*)d_in[0];
    const float* Wx  = (const float*)d_in[1];
    const float* bx  = (const float*)d_in[2];
    // d_in[3]=Wu, d_in[4]=bu unused: update gate cancels in the reference
    const float* Wr  = (const float*)d_in[5];
    const float* br  = (const float*)d_in[6];
    const float* hW  = (const float*)d_in[7];
    // d_in[8]=hUW unused
    const float* hRW = (const float*)d_in[9];
    const float* hB  = (const float*)d_in[10];
    // d_in[11]=hUB unused
    const float* hRB = (const float*)d_in[12];
    const float* h0  = (const float*)d_in[13];
    float* out = (float*)d_out;

    char* ws = (char*)d_ws;
    float* xT = (float*)(ws);                               // 32 MB
    float* xR = (float*)(ws + 33554432);                    // 32 MB
    unsigned long long* P   = (unsigned long long*)(ws + 67108864);          // 512 KB
    unsigned long long* hbc = (unsigned long long*)(ws + 67108864 + 524288); // 16 KB

    // clear tags once per launch (covers harness 0xAA poison; replay-to-replay
    // tag collisions are benign by determinism, but zeroing removes all doubt)
    hipMemsetAsync(P, 0, (2 * KWG * NN + 2 * NN) * sizeof(unsigned long long), stream);

    gemm_bias<<<dim3(16, 128), 256, 0, stream>>>(x, Wx, bx, xT);
    gemm_bias<<<dim3(16, 128), 256, 0, stream>>>(x, Wr, br, xR);

    gru_rec<<<dim3(KWG), RT, 0, stream>>>(xT, xR, hRW, hW, hRB, hB, h0,
                                          out, P, hbc);
}